// Round 3
// baseline (3230.633 us; speedup 1.0000x reference)
//
#include <hip/hip_runtime.h>
#include <hip/hip_bf16.h>
#include <math.h>

// Problem constants (fixed by the reference)
#define N_NODES 20000
#define T_STEPS 8
#define DDIM    256      // D_IN == D_HID
#define DOUT    64
#define NE      320000
#define G3      768      // 3 * DDIM

// ---------------------------------------------------------------------------
// CSR build: degree histogram -> exclusive scan -> scatter edges
// ---------------------------------------------------------------------------
__global__ void k_count(const int* __restrict__ dst, int* __restrict__ cnt) {
    int e = blockIdx.x * blockDim.x + threadIdx.x;
    if (e < NE) atomicAdd(&cnt[dst[e]], 1);
}

__global__ void k_degnorm(const int* __restrict__ cnt, float* __restrict__ dis,
                          float* __restrict__ snorm) {
    int n = blockIdx.x * blockDim.x + threadIdx.x;
    if (n < N_NODES) {
        float deg = (float)(cnt[n] + 1);   // +1 self loop
        dis[n]   = rsqrtf(deg);
        snorm[n] = 1.0f / deg;
    }
}

// single-block exclusive scan over cnt[20000] -> rowptr[20001]
__global__ void k_scan(const int* __restrict__ cnt, int* __restrict__ rowptr) {
    __shared__ int sums[256];
    const int CH = (N_NODES + 255) / 256;   // 79
    int t = threadIdx.x;
    int beg = t * CH;
    int end = beg + CH; if (end > N_NODES) end = N_NODES;
    int s = 0;
    for (int i = beg; i < end; i++) s += cnt[i];
    sums[t] = s;
    __syncthreads();
    if (t == 0) {
        int run = 0;
        for (int i = 0; i < 256; i++) { int v = sums[i]; sums[i] = run; run += v; }
    }
    __syncthreads();
    if (beg < N_NODES) {
        int run = sums[t];
        for (int i = beg; i < end; i++) { rowptr[i] = run; run += cnt[i]; }
        if (end == N_NODES) rowptr[N_NODES] = run;
    }
}

__global__ void k_fill(const int* __restrict__ src, const int* __restrict__ dst,
                       const int* __restrict__ rowptr, int* __restrict__ cursor,
                       const float* __restrict__ dis, int* __restrict__ csr_src,
                       float* __restrict__ csr_norm) {
    int e = blockIdx.x * blockDim.x + threadIdx.x;
    if (e < NE) {
        int d = dst[e], s = src[e];
        int pos = atomicAdd(&cursor[d], 1);
        int i = rowptr[d] + pos;
        if (i < NE) {                  // defensive (always true for valid input)
            csr_src[i]  = s;
            csr_norm[i] = dis[s] * dis[d];
        }
    }
}

// ---------------------------------------------------------------------------
// Weight packing: Wx3[k, 0:256|256:512|512:768] = W_xr|W_xz|W_hn
//                 Whrz[k, 0:256|256:512]        = W_hr|W_hz
// ---------------------------------------------------------------------------
__global__ void k_pack3(const float* __restrict__ Wa, const float* __restrict__ Wb,
                        const float* __restrict__ Wc, float* __restrict__ Wout) {
    int i = blockIdx.x * blockDim.x + threadIdx.x;
    if (i < DDIM * G3) {
        int k = i / G3, c = i % G3;
        float v;
        if (c < DDIM)            v = Wa[k * DDIM + c];
        else if (c < 2 * DDIM)   v = Wb[k * DDIM + (c - DDIM)];
        else                     v = Wc[k * DDIM + (c - 2 * DDIM)];
        Wout[i] = v;
    }
}
__global__ void k_pack2(const float* __restrict__ Wa, const float* __restrict__ Wb,
                        float* __restrict__ Wout) {
    int i = blockIdx.x * blockDim.x + threadIdx.x;
    if (i < DDIM * 2 * DDIM) {
        int k = i / (2 * DDIM), c = i % (2 * DDIM);
        Wout[i] = (c < DDIM) ? Wa[k * DDIM + c] : Wb[k * DDIM + (c - DDIM)];
    }
}
// bias: bx3 = [b_xr+b_hr | b_xz+b_hz | b_hn]  (h-side r,z biases folded in)
__global__ void k_packb(const float* __restrict__ bxr, const float* __restrict__ bhr,
                        const float* __restrict__ bxz, const float* __restrict__ bhz,
                        const float* __restrict__ bhn, float* __restrict__ bout) {
    int c = blockIdx.x * blockDim.x + threadIdx.x;
    if (c < G3) {
        float v;
        if (c < DDIM)          v = bxr[c] + bhr[c];
        else if (c < 2 * DDIM) v = bxz[c - DDIM] + bhz[c - DDIM];
        else                   v = bhn[c - 2 * DDIM];
        bout[c] = v;
    }
}

// ---------------------------------------------------------------------------
// Aggregation: out[n,:] = snorm[n]*in[n,:] + sum_{e: dst=n} enorm_e * in[src_e,:]
// one wave (64 lanes) per node, float4 per lane (256 floats/row)
// ---------------------------------------------------------------------------
__global__ __launch_bounds__(256) void k_agg(const float* __restrict__ in, int stride,
                      int coloff, const int* __restrict__ rowptr,
                      const int* __restrict__ csr_src, const float* __restrict__ csr_norm,
                      const float* __restrict__ snorm, float* __restrict__ out) {
    int n = blockIdx.x * 4 + (threadIdx.x >> 6);
    if (n >= N_NODES) return;
    int lane = threadIdx.x & 63;
    const float4* selfr = (const float4*)(in + (size_t)n * stride + coloff);
    float sn = snorm[n];
    float4 v = selfr[lane];
    float4 acc;
    acc.x = v.x * sn; acc.y = v.y * sn; acc.z = v.z * sn; acc.w = v.w * sn;
    int beg = rowptr[n], end = rowptr[n + 1];
    for (int i = beg; i < end; i++) {
        int s = csr_src[i];
        float w = csr_norm[i];
        float4 g = ((const float4*)(in + (size_t)s * stride + coloff))[lane];
        acc.x += g.x * w; acc.y += g.y * w; acc.z += g.z * w; acc.w += g.w * w;
    }
    ((float4*)(out + (size_t)n * DDIM))[lane] = acc;
}

// ---------------------------------------------------------------------------
// fp32 SIMT GEMM: C[M,N](ldc) = [C +] A[M,K] @ B[K,N] [+ bias]
// 128x128 tile, BK=16, 256 threads, 8x8 per thread
// acc_mode: 0 = write with bias, 1 = accumulate into existing C (no bias)
// ---------------------------------------------------------------------------
__global__ __launch_bounds__(256) void k_gemm(const float* __restrict__ A,
        const float* __restrict__ B, const float* __restrict__ bias,
        float* __restrict__ C, int M, int N, int K, int ldc, int acc_mode) {
    __shared__ float As[16][132];   // [k][row], padded
    __shared__ float Bs[16][128];   // [k][col]
    int tid = threadIdx.x;
    int tx = tid & 15, ty = tid >> 4;
    int rowBase = blockIdx.x * 128;
    int colBase = blockIdx.y * 128;

    float acc[8][8];
#pragma unroll
    for (int i = 0; i < 8; i++)
#pragma unroll
        for (int j = 0; j < 8; j++) acc[i][j] = 0.0f;

    int arow = tid >> 1;           // 0..127
    int acol = (tid & 1) * 8;      // 0 or 8
    int brow = tid >> 4;           // 0..15
    int bcol = (tid & 15) * 8;     // 0..120

    bool avalid = (rowBase + arow) < M;
    const float* Aptr = A + (size_t)(rowBase + arow) * K + acol;
    int bc = colBase + bcol;
    bool bvalid = bc < N;          // N is always a multiple of 8

    for (int k0 = 0; k0 < K; k0 += 16) {
        float4 a0 = {0,0,0,0}, a1 = {0,0,0,0};
        if (avalid) {
            a0 = *(const float4*)(Aptr + k0);
            a1 = *(const float4*)(Aptr + k0 + 4);
        }
        As[acol + 0][arow] = a0.x; As[acol + 1][arow] = a0.y;
        As[acol + 2][arow] = a0.z; As[acol + 3][arow] = a0.w;
        As[acol + 4][arow] = a1.x; As[acol + 5][arow] = a1.y;
        As[acol + 6][arow] = a1.z; As[acol + 7][arow] = a1.w;

        float4 b0 = {0,0,0,0}, b1 = {0,0,0,0};
        if (bvalid) {
            const float* Bp = B + (size_t)(k0 + brow) * N + bc;
            b0 = *(const float4*)(Bp);
            b1 = *(const float4*)(Bp + 4);
        }
        *(float4*)&Bs[brow][bcol]     = b0;
        *(float4*)&Bs[brow][bcol + 4] = b1;
        __syncthreads();

#pragma unroll
        for (int k = 0; k < 16; k++) {
            float a[8], b[8];
            *(float4*)&a[0] = *(const float4*)&As[k][ty * 8];
            *(float4*)&a[4] = *(const float4*)&As[k][ty * 8 + 4];
            *(float4*)&b[0] = *(const float4*)&Bs[k][tx * 8];
            *(float4*)&b[4] = *(const float4*)&Bs[k][tx * 8 + 4];
#pragma unroll
            for (int i = 0; i < 8; i++)
#pragma unroll
                for (int j = 0; j < 8; j++)
                    acc[i][j] = fmaf(a[i], b[j], acc[i][j]);
        }
        __syncthreads();
    }

    int c0 = colBase + tx * 8;
    if (c0 < N) {
        float4 add0 = {0,0,0,0}, add1 = {0,0,0,0};
        if (acc_mode == 0) {
            add0 = *(const float4*)(bias + c0);
            add1 = *(const float4*)(bias + c0 + 4);
        }
#pragma unroll
        for (int i = 0; i < 8; i++) {
            int r = rowBase + ty * 8 + i;
            if (r < M) {
                float* Cp = C + (size_t)r * ldc + c0;
                float4 o0, o1;
                if (acc_mode == 1) {
                    o0 = *(const float4*)(Cp);
                    o1 = *(const float4*)(Cp + 4);
                } else { o0 = add0; o1 = add1; }
                o0.x += acc[i][0]; o0.y += acc[i][1];
                o0.z += acc[i][2]; o0.w += acc[i][3];
                o1.x += acc[i][4]; o1.y += acc[i][5];
                o1.z += acc[i][6]; o1.w += acc[i][7];
                *(float4*)(Cp)     = o0;
                *(float4*)(Cp + 4) = o1;
            }
        }
    }
}

// ---------------------------------------------------------------------------
// GRU elementwise update (in place on h)
// Gx layout per node: [r_sum | z_sum | n_x] (768), Ghn per node: [n_h] (256)
// ---------------------------------------------------------------------------
__device__ __forceinline__ float sigm(float x) { return 1.0f / (1.0f + expf(-x)); }

__global__ __launch_bounds__(256) void k_gru(const float* __restrict__ Gx,
        const float* __restrict__ Ghn, float* __restrict__ h) {
    int i = blockIdx.x * blockDim.x + threadIdx.x;   // over N*D/4
    if (i >= N_NODES * DDIM / 4) return;
    int n  = i >> 6;                // / (256/4)
    int cv = (i & 63) << 2;
    size_t gb = (size_t)n * G3 + cv;
    float4 gr  = *(const float4*)(Gx + gb);             // r pre-activation
    float4 gz  = *(const float4*)(Gx + gb + DDIM);      // z pre-activation
    float4 gnx = *(const float4*)(Gx + gb + 2 * DDIM);  // n gate, x part
    float4 gnh = *(const float4*)(Ghn + (size_t)n * DDIM + cv); // n gate, h part
    float* hp = h + (size_t)n * DDIM + cv;
    float4 hv = *(float4*)hp;
    float r, z, nn;
    r = sigm(gr.x); z = sigm(gz.x);
    nn = tanhf(gnx.x + r * gnh.x); hv.x = (1.0f - z) * hv.x + z * nn;
    r = sigm(gr.y); z = sigm(gz.y);
    nn = tanhf(gnx.y + r * gnh.y); hv.y = (1.0f - z) * hv.y + z * nn;
    r = sigm(gr.z); z = sigm(gz.z);
    nn = tanhf(gnx.z + r * gnh.z); hv.z = (1.0f - z) * hv.z + z * nn;
    r = sigm(gr.w); z = sigm(gz.w);
    nn = tanhf(gnx.w + r * gnh.w); hv.w = (1.0f - z) * hv.w + z * nn;
    *(float4*)hp = hv;
}

// ---------------------------------------------------------------------------
extern "C" void kernel_launch(void* const* d_in, const int* in_sizes, int n_in,
                              void* d_out, int out_size, void* d_ws, size_t ws_size,
                              hipStream_t stream) {
    const float* x    = (const float*)d_in[0];
    const int*   eidx = (const int*)d_in[1];
    const int*   src  = eidx;
    const int*   dst  = eidx + NE;
    const float* W_xr = (const float*)d_in[2];  const float* b_xr = (const float*)d_in[3];
    const float* W_hr = (const float*)d_in[4];  const float* b_hr = (const float*)d_in[5];
    const float* W_xz = (const float*)d_in[6];  const float* b_xz = (const float*)d_in[7];
    const float* W_hz = (const float*)d_in[8];  const float* b_hz = (const float*)d_in[9];
    const float* W_hn = (const float*)d_in[10]; const float* b_hn = (const float*)d_in[11];
    const float* W_fc = (const float*)d_in[12]; const float* b_fc = (const float*)d_in[13];
    float* out = (float*)d_out;

    char* ws = (char*)d_ws;
    size_t off = 0;
    auto alloc = [&](size_t bytes) -> char* {
        char* p = ws + off;
        off += (bytes + 255) & ~(size_t)255;
        return p;
    };
    const size_t NB = (size_t)N_NODES * DDIM * 4;
    // total ~148 MB
    float* h       = (float*)alloc(NB);                           // 20.5 MB
    float* ha      = (float*)alloc(NB);                           // 20.5 MB
    float* xa      = (float*)alloc(NB);                           // 20.5 MB
    float* Gx      = (float*)alloc((size_t)N_NODES * G3 * 4);     // 61.4 MB
    float* Ghn     = (float*)alloc(NB);                           // 20.5 MB
    float* Wx3     = (float*)alloc((size_t)DDIM * G3 * 4);        // 0.79 MB
    float* Whrz    = (float*)alloc((size_t)DDIM * 2 * DDIM * 4);  // 0.52 MB
    float* bx3     = (float*)alloc(G3 * 4);
    int*   cnt     = (int*)alloc(N_NODES * 4);
    int*   cursor  = (int*)alloc(N_NODES * 4);
    int*   rowptr  = (int*)alloc((N_NODES + 1) * 4);
    int*   csr_src = (int*)alloc(NE * 4);
    float* csr_nrm = (float*)alloc(NE * 4);
    float* dis     = (float*)alloc(N_NODES * 4);
    float* snorm   = (float*)alloc(N_NODES * 4);

    hipMemsetAsync(cnt, 0, N_NODES * 4, stream);
    hipMemsetAsync(cursor, 0, N_NODES * 4, stream);
    hipMemsetAsync(h, 0, NB, stream);

    const int TB = 256;
    // CSR build + norms
    k_count<<<(NE + TB - 1) / TB, TB, 0, stream>>>(dst, cnt);
    k_degnorm<<<(N_NODES + TB - 1) / TB, TB, 0, stream>>>(cnt, dis, snorm);
    k_scan<<<1, 256, 0, stream>>>(cnt, rowptr);
    k_fill<<<(NE + TB - 1) / TB, TB, 0, stream>>>(src, dst, rowptr, cursor, dis,
                                                  csr_src, csr_nrm);
    // pack gate weights + biases
    k_pack3<<<(DDIM * G3 + TB - 1) / TB, TB, 0, stream>>>(W_xr, W_xz, W_hn, Wx3);
    k_pack2<<<(DDIM * 2 * DDIM + TB - 1) / TB, TB, 0, stream>>>(W_hr, W_hz, Whrz);
    k_packb<<<(G3 + TB - 1) / TB, TB, 0, stream>>>(b_xr, b_hr, b_xz, b_hz, b_hn, bx3);

    dim3 gG1((N_NODES + 127) / 128, G3 / 128);        // 157 x 6  (x-side, all gates)
    dim3 gG2a((N_NODES + 127) / 128, 2 * DDIM / 128); // 157 x 4  (h-side r,z accumulate)
    dim3 gG2b((N_NODES + 127) / 128, DDIM / 128);     // 157 x 2  (h-side n)
    dim3 gfc((N_NODES + 127) / 128, 1);
    int aggGrid = (N_NODES + 3) / 4;                  // 4 nodes (waves) per block
    int gruGrid = (N_NODES * DDIM / 4 + TB - 1) / TB;

    for (int t = 0; t < T_STEPS; t++) {
        k_agg<<<aggGrid, TB, 0, stream>>>(x, T_STEPS * DDIM, t * DDIM,
                                          rowptr, csr_src, csr_nrm, snorm, xa);
        k_agg<<<aggGrid, TB, 0, stream>>>(h, DDIM, 0,
                                          rowptr, csr_src, csr_nrm, snorm, ha);
        // Gx = xa @ [W_xr|W_xz|W_hn] + [bxr+bhr|bxz+bhz|bhn]
        k_gemm<<<gG1, TB, 0, stream>>>(xa, Wx3, bx3, Gx, N_NODES, G3, DDIM, G3, 0);
        // Gx[:, 0:512] += ha @ [W_hr|W_hz]
        k_gemm<<<gG2a, TB, 0, stream>>>(ha, Whrz, nullptr, Gx, N_NODES, 2 * DDIM,
                                        DDIM, G3, 1);
        // Ghn = ha @ W_hn + b_hn
        k_gemm<<<gG2b, TB, 0, stream>>>(ha, W_hn, b_hn, Ghn, N_NODES, DDIM,
                                        DDIM, DDIM, 0);
        k_gru<<<gruGrid, TB, 0, stream>>>(Gx, Ghn, h);
    }
    // final FC: out = h @ W_fc + b_fc
    k_gemm<<<gfc, TB, 0, stream>>>(h, W_fc, b_fc, out, N_NODES, DOUT, DDIM, DOUT, 0);
}

// Round 4
// 1948.613 us; speedup vs baseline: 1.6579x; 1.6579x over previous
//
#include <hip/hip_runtime.h>
#include <hip/hip_bf16.h>
#include <math.h>

// Problem constants (fixed by the reference)
#define N_NODES 20000
#define T_STEPS 8
#define DDIM    256      // D_IN == D_HID == K
#define DOUT    64
#define NE      320000
#define G3      768      // 3 * DDIM

typedef unsigned short u16;
typedef __attribute__((ext_vector_type(8))) short  short8;   // 8 bf16 = 4 VGPR
typedef __attribute__((ext_vector_type(4))) float  f32x4;

__device__ __forceinline__ float bf2f(u16 u) {
    union { unsigned int i; float f; } v; v.i = ((unsigned int)u) << 16; return v.f;
}
__device__ __forceinline__ u16 f2bf(float f) {   // RNE
    union { float f; unsigned int i; } v; v.f = f;
    unsigned int r = v.i + 0x7fff + ((v.i >> 16) & 1);
    return (u16)(r >> 16);
}

// ---------------------------------------------------------------------------
// CSR build: degree histogram -> exclusive scan -> scatter edges
// ---------------------------------------------------------------------------
__global__ void k_count(const int* __restrict__ dst, int* __restrict__ cnt) {
    int e = blockIdx.x * blockDim.x + threadIdx.x;
    if (e < NE) atomicAdd(&cnt[dst[e]], 1);
}

__global__ void k_degnorm(const int* __restrict__ cnt, float* __restrict__ dis,
                          float* __restrict__ snorm) {
    int n = blockIdx.x * blockDim.x + threadIdx.x;
    if (n < N_NODES) {
        float deg = (float)(cnt[n] + 1);   // +1 self loop
        dis[n]   = rsqrtf(deg);
        snorm[n] = 1.0f / deg;
    }
}

__global__ void k_scan(const int* __restrict__ cnt, int* __restrict__ rowptr) {
    __shared__ int sums[256];
    const int CH = (N_NODES + 255) / 256;   // 79
    int t = threadIdx.x;
    int beg = t * CH;
    int end = beg + CH; if (end > N_NODES) end = N_NODES;
    int s = 0;
    for (int i = beg; i < end; i++) s += cnt[i];
    sums[t] = s;
    __syncthreads();
    if (t == 0) {
        int run = 0;
        for (int i = 0; i < 256; i++) { int v = sums[i]; sums[i] = run; run += v; }
    }
    __syncthreads();
    if (beg < N_NODES) {
        int run = sums[t];
        for (int i = beg; i < end; i++) { rowptr[i] = run; run += cnt[i]; }
        if (end == N_NODES) rowptr[N_NODES] = run;
    }
}

__global__ void k_fill(const int* __restrict__ src, const int* __restrict__ dst,
                       const int* __restrict__ rowptr, int* __restrict__ cursor,
                       const float* __restrict__ dis, int* __restrict__ csr_src,
                       float* __restrict__ csr_norm) {
    int e = blockIdx.x * blockDim.x + threadIdx.x;
    if (e < NE) {
        int d = dst[e], s = src[e];
        int pos = atomicAdd(&cursor[d], 1);
        int i = rowptr[d] + pos;
        if (i < NE) {
            csr_src[i]  = s;
            csr_norm[i] = dis[s] * dis[d];
        }
    }
}

// ---------------------------------------------------------------------------
// Transposed bf16 weight packing: out[c][k] layout [Ncols][256]
// WxT cols: 0:256=W_xr, 256:512=W_xz, 512:768=W_hn
// WhT cols: 0:256=W_hr, 256:512=W_hz, 512:768=W_hn
// ---------------------------------------------------------------------------
__global__ void k_pack3T(const float* __restrict__ Wa, const float* __restrict__ Wb,
                         const float* __restrict__ Wc, u16* __restrict__ out) {
    int i = blockIdx.x * blockDim.x + threadIdx.x;
    if (i < G3 * DDIM) {
        int c = i >> 8, k = i & 255;
        float v;
        if (c < DDIM)            v = Wa[k * DDIM + c];
        else if (c < 2 * DDIM)   v = Wb[k * DDIM + (c - DDIM)];
        else                     v = Wc[k * DDIM + (c - 2 * DDIM)];
        out[i] = f2bf(v);
    }
}
// bias: bx3 = [b_xr+b_hr | b_xz+b_hz | b_hn]  (h-side r,z biases folded in)
__global__ void k_packb(const float* __restrict__ bxr, const float* __restrict__ bhr,
                        const float* __restrict__ bxz, const float* __restrict__ bhz,
                        const float* __restrict__ bhn, float* __restrict__ bout) {
    int c = blockIdx.x * blockDim.x + threadIdx.x;
    if (c < G3) {
        float v;
        if (c < DDIM)          v = bxr[c] + bhr[c];
        else if (c < 2 * DDIM) v = bxz[c - DDIM] + bhz[c - DDIM];
        else                   v = bhn[c - 2 * DDIM];
        bout[c] = v;
    }
}

// ---------------------------------------------------------------------------
// per-step x slice -> bf16 [N][256]
// ---------------------------------------------------------------------------
__global__ __launch_bounds__(256) void k_x2bf(const float* __restrict__ x, int t,
                                              u16* __restrict__ out) {
    int i = blockIdx.x * blockDim.x + threadIdx.x;   // over N*64
    if (i >= N_NODES * 64) return;
    int n  = i >> 6;
    int c4 = (i & 63) << 2;
    float4 v = *(const float4*)(x + (size_t)n * (T_STEPS * DDIM) + t * DDIM + c4);
    ushort4 o; o.x = f2bf(v.x); o.y = f2bf(v.y); o.z = f2bf(v.z); o.w = f2bf(v.w);
    *(ushort4*)(out + (size_t)n * DDIM + c4) = o;
}

// ---------------------------------------------------------------------------
// Aggregation (bf16 in / bf16 out):
// out[n,:] = snorm[n]*in[n,:] + sum_{e: dst=n} enorm_e * in[src_e,:]
// one wave per node, 4 bf16 (8B) per lane
// ---------------------------------------------------------------------------
__global__ __launch_bounds__(256) void k_agg_bf(const u16* __restrict__ in,
                      const int* __restrict__ rowptr, const int* __restrict__ csr_src,
                      const float* __restrict__ csr_norm, const float* __restrict__ snorm,
                      u16* __restrict__ out) {
    int n = blockIdx.x * 4 + (threadIdx.x >> 6);
    if (n >= N_NODES) return;
    int lane = threadIdx.x & 63;
    int c4 = lane << 2;
    float sn = snorm[n];
    ushort4 v = *(const ushort4*)(in + (size_t)n * DDIM + c4);
    float a0 = bf2f(v.x) * sn, a1 = bf2f(v.y) * sn, a2 = bf2f(v.z) * sn, a3 = bf2f(v.w) * sn;
    int beg = rowptr[n], end = rowptr[n + 1];
    for (int i = beg; i < end; i++) {
        int s = csr_src[i];
        float w = csr_norm[i];
        ushort4 g = *(const ushort4*)(in + (size_t)s * DDIM + c4);
        a0 = fmaf(bf2f(g.x), w, a0); a1 = fmaf(bf2f(g.y), w, a1);
        a2 = fmaf(bf2f(g.z), w, a2); a3 = fmaf(bf2f(g.w), w, a3);
    }
    ushort4 o; o.x = f2bf(a0); o.y = f2bf(a1); o.z = f2bf(a2); o.w = f2bf(a3);
    *(ushort4*)(out + (size_t)n * DDIM + c4) = o;
}

// ---------------------------------------------------------------------------
// bf16 MFMA GEMM: C[M,N](fp32,ldc) = [C +] A[M,256] @ BT[N,256]^T [+ bias]
// BM=BN=128, BK=32, 256 threads = 4 waves (2x2), each wave 64x64 via 4x4
// mfma_f32_16x16x32_bf16 fragments. Staging via global_load_lds width 16.
// acc_mode: 0 = write bias + acc, 1 = C += acc
// ---------------------------------------------------------------------------
__global__ __launch_bounds__(256) void k_gemm_bf(const u16* __restrict__ A,
        const u16* __restrict__ BT, const float* __restrict__ bias,
        float* __restrict__ C, int M, int ldc, int acc_mode) {
    __shared__ u16 As[128 * 32];   // [row][k] 8KB
    __shared__ u16 Bs[128 * 32];   // [col][k] 8KB
    int tid  = threadIdx.x;
    int wave = tid >> 6, lane = tid & 63;
    int wr = wave >> 1, wc = wave & 1;
    int rowBase = blockIdx.x * 128;
    int colBase = blockIdx.y * 128;

    // staging geometry: wave covers 2 segments of 16 rows x 32k (1KB each)
    int segr = lane >> 2;            // 0..15 row within segment
    int sege = (lane & 3) * 8;       // element offset within 32k row (16B chunks)
    int ar0 = rowBase + wave * 32 + segr;         // A rows, clamped
    int ar1 = ar0 + 16;
    if (ar0 > M - 1) ar0 = M - 1;
    if (ar1 > M - 1) ar1 = M - 1;
    size_t aoff0 = (size_t)ar0 * DDIM + sege;
    size_t aoff1 = (size_t)ar1 * DDIM + sege;
    size_t boff0 = (size_t)(colBase + wave * 32 + segr) * DDIM + sege;
    size_t boff1 = boff0 + 16 * DDIM;
    // wave-uniform LDS segment bases (bytes): wave*2048, +1024
    u16* ldsA0 = &As[wave * 1024];
    u16* ldsA1 = &As[wave * 1024 + 512];
    u16* ldsB0 = &Bs[wave * 1024];
    u16* ldsB1 = &Bs[wave * 1024 + 512];

    f32x4 acc[4][4];
#pragma unroll
    for (int m = 0; m < 4; m++)
#pragma unroll
        for (int n = 0; n < 4; n++) acc[m][n] = (f32x4){0.f, 0.f, 0.f, 0.f};

    int kq = lane >> 4;          // 0..3 (k-quarter)
    int lr = lane & 15;          // row/col within fragment

    for (int k0 = 0; k0 < DDIM; k0 += 32) {
        __builtin_amdgcn_global_load_lds(
            (const __attribute__((address_space(1))) void*)(A + aoff0 + k0),
            (__attribute__((address_space(3))) void*)ldsA0, 16, 0, 0);
        __builtin_amdgcn_global_load_lds(
            (const __attribute__((address_space(1))) void*)(A + aoff1 + k0),
            (__attribute__((address_space(3))) void*)ldsA1, 16, 0, 0);
        __builtin_amdgcn_global_load_lds(
            (const __attribute__((address_space(1))) void*)(BT + boff0 + k0),
            (__attribute__((address_space(3))) void*)ldsB0, 16, 0, 0);
        __builtin_amdgcn_global_load_lds(
            (const __attribute__((address_space(1))) void*)(BT + boff1 + k0),
            (__attribute__((address_space(3))) void*)ldsB1, 16, 0, 0);
        __syncthreads();   // drains vmcnt before barrier (compiler-inserted)

        short8 af[4], bf[4];
#pragma unroll
        for (int m = 0; m < 4; m++)
            af[m] = *(const short8*)&As[(wr * 64 + m * 16 + lr) * 32 + kq * 8];
#pragma unroll
        for (int n = 0; n < 4; n++)
            bf[n] = *(const short8*)&Bs[(wc * 64 + n * 16 + lr) * 32 + kq * 8];
#pragma unroll
        for (int m = 0; m < 4; m++)
#pragma unroll
            for (int n = 0; n < 4; n++)
                acc[m][n] = __builtin_amdgcn_mfma_f32_16x16x32_bf16(
                    af[m], bf[n], acc[m][n], 0, 0, 0);
        __syncthreads();   // all reads done before next stage overwrites
    }

    // epilogue: C[row = rowBase+wr*64+m*16+kq*4+j][col = colBase+wc*64+n*16+lr]
#pragma unroll
    for (int n = 0; n < 4; n++) {
        int col = colBase + wc * 64 + n * 16 + lr;
        float bv = (acc_mode == 0) ? bias[col] : 0.0f;
#pragma unroll
        for (int m = 0; m < 4; m++) {
            int row0 = rowBase + wr * 64 + m * 16 + kq * 4;
#pragma unroll
            for (int j = 0; j < 4; j++) {
                int row = row0 + j;
                if (row < M) {
                    float* p = C + (size_t)row * ldc + col;
                    float v = acc[m][n][j];
                    if (acc_mode == 1) v += *p; else v += bv;
                    *p = v;
                }
            }
        }
    }
}

// ---------------------------------------------------------------------------
// fp32 SIMT GEMM (final FC only): C[M,N] = A[M,K] @ B[K,N] + bias
// ---------------------------------------------------------------------------
__global__ __launch_bounds__(256) void k_gemm(const float* __restrict__ A,
        const float* __restrict__ B, const float* __restrict__ bias,
        float* __restrict__ C, int M, int N, int K) {
    __shared__ float Asm[16][132];
    __shared__ float Bsm[16][128];
    int tid = threadIdx.x;
    int tx = tid & 15, ty = tid >> 4;
    int rowBase = blockIdx.x * 128;
    int colBase = blockIdx.y * 128;

    float acc[8][8];
#pragma unroll
    for (int i = 0; i < 8; i++)
#pragma unroll
        for (int j = 0; j < 8; j++) acc[i][j] = 0.0f;

    int arow = tid >> 1;
    int acol = (tid & 1) * 8;
    int brow = tid >> 4;
    int bcol = (tid & 15) * 8;

    bool avalid = (rowBase + arow) < M;
    const float* Aptr = A + (size_t)(rowBase + arow) * K + acol;
    int bc = colBase + bcol;
    bool bvalid = bc < N;

    for (int k0 = 0; k0 < K; k0 += 16) {
        float4 a0 = {0,0,0,0}, a1 = {0,0,0,0};
        if (avalid) {
            a0 = *(const float4*)(Aptr + k0);
            a1 = *(const float4*)(Aptr + k0 + 4);
        }
        Asm[acol + 0][arow] = a0.x; Asm[acol + 1][arow] = a0.y;
        Asm[acol + 2][arow] = a0.z; Asm[acol + 3][arow] = a0.w;
        Asm[acol + 4][arow] = a1.x; Asm[acol + 5][arow] = a1.y;
        Asm[acol + 6][arow] = a1.z; Asm[acol + 7][arow] = a1.w;

        float4 b0 = {0,0,0,0}, b1 = {0,0,0,0};
        if (bvalid) {
            const float* Bp = B + (size_t)(k0 + brow) * N + bc;
            b0 = *(const float4*)(Bp);
            b1 = *(const float4*)(Bp + 4);
        }
        *(float4*)&Bsm[brow][bcol]     = b0;
        *(float4*)&Bsm[brow][bcol + 4] = b1;
        __syncthreads();

#pragma unroll
        for (int k = 0; k < 16; k++) {
            float a[8], b[8];
            *(float4*)&a[0] = *(const float4*)&Asm[k][ty * 8];
            *(float4*)&a[4] = *(const float4*)&Asm[k][ty * 8 + 4];
            *(float4*)&b[0] = *(const float4*)&Bsm[k][tx * 8];
            *(float4*)&b[4] = *(const float4*)&Bsm[k][tx * 8 + 4];
#pragma unroll
            for (int i = 0; i < 8; i++)
#pragma unroll
                for (int j = 0; j < 8; j++)
                    acc[i][j] = fmaf(a[i], b[j], acc[i][j]);
        }
        __syncthreads();
    }

    int c0 = colBase + tx * 8;
    if (c0 < N) {
        float4 bia0 = *(const float4*)(bias + c0);
        float4 bia1 = *(const float4*)(bias + c0 + 4);
#pragma unroll
        for (int i = 0; i < 8; i++) {
            int r = rowBase + ty * 8 + i;
            if (r < M) {
                float4 o0, o1;
                o0.x = acc[i][0] + bia0.x; o0.y = acc[i][1] + bia0.y;
                o0.z = acc[i][2] + bia0.z; o0.w = acc[i][3] + bia0.w;
                o1.x = acc[i][4] + bia1.x; o1.y = acc[i][5] + bia1.y;
                o1.z = acc[i][6] + bia1.z; o1.w = acc[i][7] + bia1.w;
                *(float4*)(C + (size_t)r * N + c0)     = o0;
                *(float4*)(C + (size_t)r * N + c0 + 4) = o1;
            }
        }
    }
}

// ---------------------------------------------------------------------------
// GRU elementwise update: h (fp32, in place) + hbf (bf16 copy for gathering)
// Gx per node: [r_sum | z_sum | n_x] (768), Ghn per node: [n_h] (256)
// ---------------------------------------------------------------------------
__device__ __forceinline__ float sigm(float x) { return 1.0f / (1.0f + expf(-x)); }

__global__ __launch_bounds__(256) void k_gru(const float* __restrict__ Gx,
        const float* __restrict__ Ghn, float* __restrict__ h, u16* __restrict__ hbf) {
    int i = blockIdx.x * blockDim.x + threadIdx.x;   // over N*D/4
    if (i >= N_NODES * DDIM / 4) return;
    int n  = i >> 6;
    int cv = (i & 63) << 2;
    size_t gb = (size_t)n * G3 + cv;
    float4 gr  = *(const float4*)(Gx + gb);
    float4 gz  = *(const float4*)(Gx + gb + DDIM);
    float4 gnx = *(const float4*)(Gx + gb + 2 * DDIM);
    float4 gnh = *(const float4*)(Ghn + (size_t)n * DDIM + cv);
    float* hp = h + (size_t)n * DDIM + cv;
    float4 hv = *(float4*)hp;
    float r, z, nn;
    r = sigm(gr.x); z = sigm(gz.x);
    nn = tanhf(gnx.x + r * gnh.x); hv.x = (1.0f - z) * hv.x + z * nn;
    r = sigm(gr.y); z = sigm(gz.y);
    nn = tanhf(gnx.y + r * gnh.y); hv.y = (1.0f - z) * hv.y + z * nn;
    r = sigm(gr.z); z = sigm(gz.z);
    nn = tanhf(gnx.z + r * gnh.z); hv.z = (1.0f - z) * hv.z + z * nn;
    r = sigm(gr.w); z = sigm(gz.w);
    nn = tanhf(gnx.w + r * gnh.w); hv.w = (1.0f - z) * hv.w + z * nn;
    *(float4*)hp = hv;
    ushort4 hb; hb.x = f2bf(hv.x); hb.y = f2bf(hv.y); hb.z = f2bf(hv.z); hb.w = f2bf(hv.w);
    *(ushort4*)(hbf + (size_t)n * DDIM + cv) = hb;
}

// ---------------------------------------------------------------------------
extern "C" void kernel_launch(void* const* d_in, const int* in_sizes, int n_in,
                              void* d_out, int out_size, void* d_ws, size_t ws_size,
                              hipStream_t stream) {
    const float* x    = (const float*)d_in[0];
    const int*   eidx = (const int*)d_in[1];
    const int*   src  = eidx;
    const int*   dst  = eidx + NE;
    const float* W_xr = (const float*)d_in[2];  const float* b_xr = (const float*)d_in[3];
    const float* W_hr = (const float*)d_in[4];  const float* b_hr = (const float*)d_in[5];
    const float* W_xz = (const float*)d_in[6];  const float* b_xz = (const float*)d_in[7];
    const float* W_hz = (const float*)d_in[8];  const float* b_hz = (const float*)d_in[9];
    const float* W_hn = (const float*)d_in[10]; const float* b_hn = (const float*)d_in[11];
    const float* W_fc = (const float*)d_in[12]; const float* b_fc = (const float*)d_in[13];
    float* out = (float*)d_out;

    char* ws = (char*)d_ws;
    size_t off = 0;
    auto alloc = [&](size_t bytes) -> char* {
        char* p = ws + off;
        off += (bytes + 255) & ~(size_t)255;
        return p;
    };
    const size_t NB  = (size_t)N_NODES * DDIM * 4;   // 20.5 MB fp32
    const size_t NBH = (size_t)N_NODES * DDIM * 2;   // 10.2 MB bf16
    float* h       = (float*)alloc(NB);
    u16*   hbf     = (u16*)alloc(NBH);
    u16*   xtbf    = (u16*)alloc(NBH);
    u16*   xa      = (u16*)alloc(NBH);
    u16*   ha      = (u16*)alloc(NBH);
    float* Gx      = (float*)alloc((size_t)N_NODES * G3 * 4);   // 61.4 MB
    float* Ghn     = (float*)alloc(NB);
    u16*   WxT     = (u16*)alloc((size_t)G3 * DDIM * 2);
    u16*   WhT     = (u16*)alloc((size_t)G3 * DDIM * 2);
    float* bx3     = (float*)alloc(G3 * 4);
    int*   cnt     = (int*)alloc(N_NODES * 4);
    int*   cursor  = (int*)alloc(N_NODES * 4);
    int*   rowptr  = (int*)alloc((N_NODES + 1) * 4);
    int*   csr_src = (int*)alloc(NE * 4);
    float* csr_nrm = (float*)alloc(NE * 4);
    float* dis     = (float*)alloc(N_NODES * 4);
    float* snorm   = (float*)alloc(N_NODES * 4);

    hipMemsetAsync(cnt, 0, N_NODES * 4, stream);
    hipMemsetAsync(cursor, 0, N_NODES * 4, stream);
    hipMemsetAsync(h, 0, NB, stream);
    hipMemsetAsync(hbf, 0, NBH, stream);

    const int TB = 256;
    // CSR build + norms
    k_count<<<(NE + TB - 1) / TB, TB, 0, stream>>>(dst, cnt);
    k_degnorm<<<(N_NODES + TB - 1) / TB, TB, 0, stream>>>(cnt, dis, snorm);
    k_scan<<<1, 256, 0, stream>>>(cnt, rowptr);
    k_fill<<<(NE + TB - 1) / TB, TB, 0, stream>>>(src, dst, rowptr, cursor, dis,
                                                  csr_src, csr_nrm);
    // pack transposed bf16 weights + fused biases
    k_pack3T<<<(G3 * DDIM + TB - 1) / TB, TB, 0, stream>>>(W_xr, W_xz, W_hn, WxT);
    k_pack3T<<<(G3 * DDIM + TB - 1) / TB, TB, 0, stream>>>(W_hr, W_hz, W_hn, WhT);
    k_packb<<<(G3 + TB - 1) / TB, TB, 0, stream>>>(b_xr, b_hr, b_xz, b_hz, b_hn, bx3);

    dim3 gG1((N_NODES + 127) / 128, G3 / 128);        // 157 x 6  (x-side all gates)
    dim3 gG2a((N_NODES + 127) / 128, 2 * DDIM / 128); // 157 x 4  (h-side r,z accum)
    dim3 gG2b((N_NODES + 127) / 128, DDIM / 128);     // 157 x 2  (h-side n)
    dim3 gfc((N_NODES + 127) / 128, 1);
    int aggGrid = (N_NODES + 3) / 4;
    int cvtGrid = (N_NODES * 64 + TB - 1) / TB;
    int gruGrid = (N_NODES * DDIM / 4 + TB - 1) / TB;

    for (int t = 0; t < T_STEPS; t++) {
        k_x2bf<<<cvtGrid, TB, 0, stream>>>(x, t, xtbf);
        k_agg_bf<<<aggGrid, TB, 0, stream>>>(xtbf, rowptr, csr_src, csr_nrm, snorm, xa);
        k_agg_bf<<<aggGrid, TB, 0, stream>>>(hbf, rowptr, csr_src, csr_nrm, snorm, ha);
        // Gx = xa @ [W_xr|W_xz|W_hn] + [bxr+bhr|bxz+bhz|bhn]
        k_gemm_bf<<<gG1, TB, 0, stream>>>(xa, WxT, bx3, Gx, N_NODES, G3, 0);
        // Gx[:, 0:512] += ha @ [W_hr|W_hz]
        k_gemm_bf<<<gG2a, TB, 0, stream>>>(ha, WhT, nullptr, Gx, N_NODES, G3, 1);
        // Ghn = ha @ W_hn + b_hn
        k_gemm_bf<<<gG2b, TB, 0, stream>>>(ha, WhT + 512 * DDIM, b_hn, Ghn,
                                           N_NODES, DDIM, 0);
        k_gru<<<gruGrid, TB, 0, stream>>>(Gx, Ghn, h, hbf);
    }
    // final FC in fp32: out = h @ W_fc + b_fc
    k_gemm<<<gfc, TB, 0, stream>>>(h, W_fc, b_fc, out, N_NODES, DOUT, DDIM);
}

// Round 5
// 1437.280 us; speedup vs baseline: 2.2477x; 1.3558x over previous
//
#include <hip/hip_runtime.h>
#include <hip/hip_bf16.h>
#include <math.h>

// Problem constants (fixed by the reference)
#define N_NODES 20000
#define T_STEPS 8
#define DDIM    256      // D_IN == D_HID == K
#define DOUT    64
#define NE      320000
#define G4      1024     // packed gate cols: [r | z | n_x | n_h]
#define XSTR    2048     // T_STEPS * DDIM

typedef unsigned short u16;
typedef __attribute__((ext_vector_type(8))) short  short8;   // 8 bf16 = 4 VGPR
typedef __attribute__((ext_vector_type(4))) float  f32x4;

__device__ __forceinline__ float bf2f(u16 u) {
    union { unsigned int i; float f; } v; v.i = ((unsigned int)u) << 16; return v.f;
}
__device__ __forceinline__ u16 f2bf(float f) {   // RNE
    union { float f; unsigned int i; } v; v.f = f;
    unsigned int r = v.i + 0x7fff + ((v.i >> 16) & 1);
    return (u16)(r >> 16);
}

// ---------------------------------------------------------------------------
// CSR build
// ---------------------------------------------------------------------------
__global__ void k_count(const int* __restrict__ dst, int* __restrict__ cnt) {
    int e = blockIdx.x * blockDim.x + threadIdx.x;
    if (e < NE) atomicAdd(&cnt[dst[e]], 1);
}

__global__ void k_degnorm(const int* __restrict__ cnt, float* __restrict__ dis,
                          float* __restrict__ snorm) {
    int n = blockIdx.x * blockDim.x + threadIdx.x;
    if (n < N_NODES) {
        float deg = (float)(cnt[n] + 1);   // +1 self loop
        dis[n]   = rsqrtf(deg);
        snorm[n] = 1.0f / deg;
    }
}

__global__ void k_scan(const int* __restrict__ cnt, int* __restrict__ rowptr) {
    __shared__ int sums[256];
    const int CH = (N_NODES + 255) / 256;   // 79
    int t = threadIdx.x;
    int beg = t * CH;
    int end = beg + CH; if (end > N_NODES) end = N_NODES;
    int s = 0;
    for (int i = beg; i < end; i++) s += cnt[i];
    sums[t] = s;
    __syncthreads();
    if (t == 0) {
        int run = 0;
        for (int i = 0; i < 256; i++) { int v = sums[i]; sums[i] = run; run += v; }
    }
    __syncthreads();
    if (beg < N_NODES) {
        int run = sums[t];
        for (int i = beg; i < end; i++) { rowptr[i] = run; run += cnt[i]; }
        if (end == N_NODES) rowptr[N_NODES] = run;
    }
}

__global__ void k_fill(const int* __restrict__ src, const int* __restrict__ dst,
                       const int* __restrict__ rowptr, int* __restrict__ cursor,
                       const float* __restrict__ dis, int* __restrict__ csr_src,
                       float* __restrict__ csr_norm) {
    int e = blockIdx.x * blockDim.x + threadIdx.x;
    if (e < NE) {
        int d = dst[e], s = src[e];
        int pos = atomicAdd(&cursor[d], 1);
        int i = rowptr[d] + pos;
        if (i < NE) {
            csr_src[i]  = s;
            csr_norm[i] = dis[s] * dis[d];
        }
    }
}

// ---------------------------------------------------------------------------
// Transposed bf16 weight packing: BT[c][k], c in [0,1024), 4 quarters
// ---------------------------------------------------------------------------
__global__ void k_pack4T(const float* __restrict__ Wa, const float* __restrict__ Wb,
                         const float* __restrict__ Wc, const float* __restrict__ Wd,
                         u16* __restrict__ out) {
    int i = blockIdx.x * blockDim.x + threadIdx.x;
    if (i < G4 * DDIM) {
        int c = i >> 8, k = i & 255;
        const float* W = (c < 256) ? Wa : (c < 512) ? Wb : (c < 768) ? Wc : Wd;
        int cc = c & 255;
        out[i] = f2bf(W[k * DDIM + cc]);
    }
}
// bias4 = [b_xr+b_hr | b_xz+b_hz | b_hn | b_hn]
__global__ void k_packb4(const float* __restrict__ bxr, const float* __restrict__ bhr,
                         const float* __restrict__ bxz, const float* __restrict__ bhz,
                         const float* __restrict__ bhn, float* __restrict__ bout) {
    int c = blockIdx.x * blockDim.x + threadIdx.x;
    if (c < G4) {
        float v;
        if (c < 256)      v = bxr[c] + bhr[c];
        else if (c < 512) v = bxz[c - 256] + bhz[c - 256];
        else              v = bhn[c & 255];
        bout[c] = v;
    }
}

// ---------------------------------------------------------------------------
// all-timestep x -> bf16 [N][2048]
// ---------------------------------------------------------------------------
__global__ __launch_bounds__(256) void k_x2bf_all(const float* __restrict__ x,
                                                  u16* __restrict__ out) {
    int i = blockIdx.x * blockDim.x + threadIdx.x;   // over N*512 ushort4 chunks
    if (i >= N_NODES * 512) return;
    size_t o = (size_t)i << 2;
    float4 v = *(const float4*)(x + o);
    ushort4 u; u.x = f2bf(v.x); u.y = f2bf(v.y); u.z = f2bf(v.z); u.w = f2bf(v.w);
    *(ushort4*)(out + o) = u;
}

// ---------------------------------------------------------------------------
// Batched x aggregation over all 8 timesteps:
// xaall[n][t*256+c] = snorm[n]*xall[n][t*256+c] + sum_e enorm_e * xall[src][t*256+c]
// one wave per node; per edge, 8 independent 8B gathers per lane (MLP)
// ---------------------------------------------------------------------------
__global__ __launch_bounds__(256) void k_agg_x(const u16* __restrict__ xall,
                      const int* __restrict__ rowptr, const int* __restrict__ csr_src,
                      const float* __restrict__ csr_norm, const float* __restrict__ snorm,
                      u16* __restrict__ xaall) {
    int n = blockIdx.x * 4 + (threadIdx.x >> 6);
    if (n >= N_NODES) return;
    int lane = threadIdx.x & 63;
    int c4 = lane << 2;
    float sn = snorm[n];
    float acc[8][4];
    const u16* selfp = xall + (size_t)n * XSTR + c4;
#pragma unroll
    for (int t = 0; t < 8; t++) {
        ushort4 v = *(const ushort4*)(selfp + t * DDIM);
        acc[t][0] = bf2f(v.x) * sn; acc[t][1] = bf2f(v.y) * sn;
        acc[t][2] = bf2f(v.z) * sn; acc[t][3] = bf2f(v.w) * sn;
    }
    int beg = rowptr[n], end = rowptr[n + 1];
    for (int i = beg; i < end; i++) {
        const u16* sp = xall + (size_t)csr_src[i] * XSTR + c4;
        float w = csr_norm[i];
        ushort4 g[8];
#pragma unroll
        for (int t = 0; t < 8; t++) g[t] = *(const ushort4*)(sp + t * DDIM);
#pragma unroll
        for (int t = 0; t < 8; t++) {
            acc[t][0] = fmaf(bf2f(g[t].x), w, acc[t][0]);
            acc[t][1] = fmaf(bf2f(g[t].y), w, acc[t][1]);
            acc[t][2] = fmaf(bf2f(g[t].z), w, acc[t][2]);
            acc[t][3] = fmaf(bf2f(g[t].w), w, acc[t][3]);
        }
    }
    u16* op = xaall + (size_t)n * XSTR + c4;
#pragma unroll
    for (int t = 0; t < 8; t++) {
        ushort4 o;
        o.x = f2bf(acc[t][0]); o.y = f2bf(acc[t][1]);
        o.z = f2bf(acc[t][2]); o.w = f2bf(acc[t][3]);
        *(ushort4*)(op + t * DDIM) = o;
    }
}

// ---------------------------------------------------------------------------
// Per-step h aggregation (bf16 in/out), one wave per node
// ---------------------------------------------------------------------------
__global__ __launch_bounds__(256) void k_agg_bf(const u16* __restrict__ in,
                      const int* __restrict__ rowptr, const int* __restrict__ csr_src,
                      const float* __restrict__ csr_norm, const float* __restrict__ snorm,
                      u16* __restrict__ out) {
    int n = blockIdx.x * 4 + (threadIdx.x >> 6);
    if (n >= N_NODES) return;
    int lane = threadIdx.x & 63;
    int c4 = lane << 2;
    float sn = snorm[n];
    ushort4 v = *(const ushort4*)(in + (size_t)n * DDIM + c4);
    float a0 = bf2f(v.x) * sn, a1 = bf2f(v.y) * sn, a2 = bf2f(v.z) * sn, a3 = bf2f(v.w) * sn;
    int beg = rowptr[n], end = rowptr[n + 1];
    for (int i = beg; i < end; i++) {
        int s = csr_src[i];
        float w = csr_norm[i];
        ushort4 g = *(const ushort4*)(in + (size_t)s * DDIM + c4);
        a0 = fmaf(bf2f(g.x), w, a0); a1 = fmaf(bf2f(g.y), w, a1);
        a2 = fmaf(bf2f(g.z), w, a2); a3 = fmaf(bf2f(g.w), w, a3);
    }
    ushort4 o; o.x = f2bf(a0); o.y = f2bf(a1); o.z = f2bf(a2); o.w = f2bf(a3);
    *(ushort4*)(out + (size_t)n * DDIM + c4) = o;
}

// ---------------------------------------------------------------------------
// Merged gate GEMM: G[M][1024] = bias4 + per-col-group:
//   cols 0:512   = xa@BTA + ha@BTB   (r_pre, z_pre)
//   cols 512:768 = xa@W_hn           (n_x;  BTA cols 512:768)
//   cols 768:1024= ha@W_hn           (n_h;  BTB cols 768:1024)
// BM=BN=128, BK=32, 4 waves (2x2), wave 64x64 via 4x4 mfma_f32_16x16x32_bf16.
// LDS chunk-XOR swizzle: LDS[row][cp] = global[row][cp ^ ((row>>1)&3)],
// applied on the global source (staging) and the read side (involution).
// ---------------------------------------------------------------------------
__global__ __launch_bounds__(256) void k_gemm_gate(const u16* __restrict__ xa, int ldax,
        const u16* __restrict__ ha, const u16* __restrict__ BTA,
        const u16* __restrict__ BTB, const float* __restrict__ bias4,
        float* __restrict__ G, int M) {
    __shared__ u16 As[128 * 32];   // 8KB
    __shared__ u16 Bs[128 * 32];   // 8KB
    int tid  = threadIdx.x;
    int wave = tid >> 6, lane = tid & 63;
    int wr = wave >> 1, wc = wave & 1;
    int rowBase = blockIdx.x * 128;
    int cy = blockIdx.y;               // 0..7 col-tile of 128
    int colBase = cy * 128;
    bool use_x = (cy < 6);
    bool use_h = (cy < 4) || (cy >= 6);

    // staging geometry (per wave: 2 segments of 16 rows x 32k)
    int segr  = lane >> 2;                               // 0..15
    int chunk = (lane & 3) ^ ((segr >> 1) & 3);          // swizzled source chunk
    int sege  = chunk * 8;                               // element offset
    int ar0 = rowBase + wave * 32 + segr;
    int ar1 = ar0 + 16;
    if (ar0 > M - 1) ar0 = M - 1;
    if (ar1 > M - 1) ar1 = M - 1;
    int br0 = colBase + wave * 32 + segr;                // BT row (G col)
    size_t boff0 = (size_t)br0 * DDIM + sege;
    size_t boff1 = boff0 + 16 * DDIM;
    u16* ldsA0 = &As[wave * 1024];
    u16* ldsA1 = &As[wave * 1024 + 512];
    u16* ldsB0 = &Bs[wave * 1024];
    u16* ldsB1 = &Bs[wave * 1024 + 512];

    f32x4 acc[4][4];
#pragma unroll
    for (int m = 0; m < 4; m++)
#pragma unroll
        for (int n = 0; n < 4; n++) acc[m][n] = (f32x4){0.f, 0.f, 0.f, 0.f};

    int kq  = lane >> 4;                     // 0..3
    int lr  = lane & 15;
    int kqs = (kq ^ ((lr >> 1) & 3)) << 3;   // swizzled read chunk (elements)

    for (int chain = 0; chain < 2; chain++) {
        bool active = (chain == 0) ? use_x : use_h;
        if (!active) continue;
        const u16* Aop = (chain == 0) ? xa : ha;
        int lda        = (chain == 0) ? ldax : DDIM;
        const u16* BT  = (chain == 0) ? BTA : BTB;
        size_t aoff0 = (size_t)ar0 * lda + sege;
        size_t aoff1 = (size_t)ar1 * lda + sege;

        for (int k0 = 0; k0 < DDIM; k0 += 32) {
            __builtin_amdgcn_global_load_lds(
                (const __attribute__((address_space(1))) void*)(Aop + aoff0 + k0),
                (__attribute__((address_space(3))) void*)ldsA0, 16, 0, 0);
            __builtin_amdgcn_global_load_lds(
                (const __attribute__((address_space(1))) void*)(Aop + aoff1 + k0),
                (__attribute__((address_space(3))) void*)ldsA1, 16, 0, 0);
            __builtin_amdgcn_global_load_lds(
                (const __attribute__((address_space(1))) void*)(BT + boff0 + k0),
                (__attribute__((address_space(3))) void*)ldsB0, 16, 0, 0);
            __builtin_amdgcn_global_load_lds(
                (const __attribute__((address_space(1))) void*)(BT + boff1 + k0),
                (__attribute__((address_space(3))) void*)ldsB1, 16, 0, 0);
            __syncthreads();

            short8 af[4], bf[4];
#pragma unroll
            for (int m = 0; m < 4; m++)
                af[m] = *(const short8*)&As[(wr * 64 + m * 16 + lr) * 32 + kqs];
#pragma unroll
            for (int n = 0; n < 4; n++)
                bf[n] = *(const short8*)&Bs[(wc * 64 + n * 16 + lr) * 32 + kqs];
#pragma unroll
            for (int m = 0; m < 4; m++)
#pragma unroll
                for (int n = 0; n < 4; n++)
                    acc[m][n] = __builtin_amdgcn_mfma_f32_16x16x32_bf16(
                        af[m], bf[n], acc[m][n], 0, 0, 0);
            __syncthreads();
        }
    }

    // epilogue: G[row][col], col = colBase+wc*64+n*16+lr, row = rowBase+wr*64+m*16+kq*4+j
#pragma unroll
    for (int n = 0; n < 4; n++) {
        int col = colBase + wc * 64 + n * 16 + lr;
        float bv = bias4[col];
#pragma unroll
        for (int m = 0; m < 4; m++) {
            int row0 = rowBase + wr * 64 + m * 16 + kq * 4;
#pragma unroll
            for (int j = 0; j < 4; j++) {
                int row = row0 + j;
                if (row < M)
                    G[(size_t)row * G4 + col] = acc[m][n][j] + bv;
            }
        }
    }
}

// ---------------------------------------------------------------------------
// fp32 SIMT GEMM (final FC only)
// ---------------------------------------------------------------------------
__global__ __launch_bounds__(256) void k_gemm(const float* __restrict__ A,
        const float* __restrict__ B, const float* __restrict__ bias,
        float* __restrict__ C, int M, int N, int K) {
    __shared__ float Asm[16][132];
    __shared__ float Bsm[16][128];
    int tid = threadIdx.x;
    int tx = tid & 15, ty = tid >> 4;
    int rowBase = blockIdx.x * 128;
    int colBase = blockIdx.y * 128;

    float acc[8][8];
#pragma unroll
    for (int i = 0; i < 8; i++)
#pragma unroll
        for (int j = 0; j < 8; j++) acc[i][j] = 0.0f;

    int arow = tid >> 1;
    int acol = (tid & 1) * 8;
    int brow = tid >> 4;
    int bcol = (tid & 15) * 8;

    bool avalid = (rowBase + arow) < M;
    const float* Aptr = A + (size_t)(rowBase + arow) * K + acol;
    int bc = colBase + bcol;
    bool bvalid = bc < N;

    for (int k0 = 0; k0 < K; k0 += 16) {
        float4 a0 = {0,0,0,0}, a1 = {0,0,0,0};
        if (avalid) {
            a0 = *(const float4*)(Aptr + k0);
            a1 = *(const float4*)(Aptr + k0 + 4);
        }
        Asm[acol + 0][arow] = a0.x; Asm[acol + 1][arow] = a0.y;
        Asm[acol + 2][arow] = a0.z; Asm[acol + 3][arow] = a0.w;
        Asm[acol + 4][arow] = a1.x; Asm[acol + 5][arow] = a1.y;
        Asm[acol + 6][arow] = a1.z; Asm[acol + 7][arow] = a1.w;

        float4 b0 = {0,0,0,0}, b1 = {0,0,0,0};
        if (bvalid) {
            const float* Bp = B + (size_t)(k0 + brow) * N + bc;
            b0 = *(const float4*)(Bp);
            b1 = *(const float4*)(Bp + 4);
        }
        *(float4*)&Bsm[brow][bcol]     = b0;
        *(float4*)&Bsm[brow][bcol + 4] = b1;
        __syncthreads();

#pragma unroll
        for (int k = 0; k < 16; k++) {
            float a[8], b[8];
            *(float4*)&a[0] = *(const float4*)&Asm[k][ty * 8];
            *(float4*)&a[4] = *(const float4*)&Asm[k][ty * 8 + 4];
            *(float4*)&b[0] = *(const float4*)&Bsm[k][tx * 8];
            *(float4*)&b[4] = *(const float4*)&Bsm[k][tx * 8 + 4];
#pragma unroll
            for (int i = 0; i < 8; i++)
#pragma unroll
                for (int j = 0; j < 8; j++)
                    acc[i][j] = fmaf(a[i], b[j], acc[i][j]);
        }
        __syncthreads();
    }

    int c0 = colBase + tx * 8;
    if (c0 < N) {
        float4 bia0 = *(const float4*)(bias + c0);
        float4 bia1 = *(const float4*)(bias + c0 + 4);
#pragma unroll
        for (int i = 0; i < 8; i++) {
            int r = rowBase + ty * 8 + i;
            if (r < M) {
                float4 o0, o1;
                o0.x = acc[i][0] + bia0.x; o0.y = acc[i][1] + bia0.y;
                o0.z = acc[i][2] + bia0.z; o0.w = acc[i][3] + bia0.w;
                o1.x = acc[i][4] + bia1.x; o1.y = acc[i][5] + bia1.y;
                o1.z = acc[i][6] + bia1.z; o1.w = acc[i][7] + bia1.w;
                *(float4*)(C + (size_t)r * N + c0)     = o0;
                *(float4*)(C + (size_t)r * N + c0 + 4) = o1;
            }
        }
    }
}

// ---------------------------------------------------------------------------
// GRU elementwise update: reads G[N][1024] = [r|z|n_x|n_h], updates h (+hbf)
// ---------------------------------------------------------------------------
__device__ __forceinline__ float sigm(float x) { return 1.0f / (1.0f + expf(-x)); }

__global__ __launch_bounds__(256) void k_gru(const float* __restrict__ G,
        float* __restrict__ h, u16* __restrict__ hbf) {
    int i = blockIdx.x * blockDim.x + threadIdx.x;   // over N*D/4
    if (i >= N_NODES * DDIM / 4) return;
    int n  = i >> 6;
    int cv = (i & 63) << 2;
    size_t gb = (size_t)n * G4 + cv;
    float4 gr  = *(const float4*)(G + gb);
    float4 gz  = *(const float4*)(G + gb + 256);
    float4 gnx = *(const float4*)(G + gb + 512);
    float4 gnh = *(const float4*)(G + gb + 768);
    float* hp = h + (size_t)n * DDIM + cv;
    float4 hv = *(float4*)hp;
    float r, z, nn;
    r = sigm(gr.x); z = sigm(gz.x);
    nn = tanhf(gnx.x + r * gnh.x); hv.x = (1.0f - z) * hv.x + z * nn;
    r = sigm(gr.y); z = sigm(gz.y);
    nn = tanhf(gnx.y + r * gnh.y); hv.y = (1.0f - z) * hv.y + z * nn;
    r = sigm(gr.z); z = sigm(gz.z);
    nn = tanhf(gnx.z + r * gnh.z); hv.z = (1.0f - z) * hv.z + z * nn;
    r = sigm(gr.w); z = sigm(gz.w);
    nn = tanhf(gnx.w + r * gnh.w); hv.w = (1.0f - z) * hv.w + z * nn;
    *(float4*)hp = hv;
    ushort4 hb; hb.x = f2bf(hv.x); hb.y = f2bf(hv.y); hb.z = f2bf(hv.z); hb.w = f2bf(hv.w);
    *(ushort4*)(hbf + (size_t)n * DDIM + cv) = hb;
}

// ---------------------------------------------------------------------------
extern "C" void kernel_launch(void* const* d_in, const int* in_sizes, int n_in,
                              void* d_out, int out_size, void* d_ws, size_t ws_size,
                              hipStream_t stream) {
    const float* x    = (const float*)d_in[0];
    const int*   eidx = (const int*)d_in[1];
    const int*   src  = eidx;
    const int*   dst  = eidx + NE;
    const float* W_xr = (const float*)d_in[2];  const float* b_xr = (const float*)d_in[3];
    const float* W_hr = (const float*)d_in[4];  const float* b_hr = (const float*)d_in[5];
    const float* W_xz = (const float*)d_in[6];  const float* b_xz = (const float*)d_in[7];
    const float* W_hz = (const float*)d_in[8];  const float* b_hz = (const float*)d_in[9];
    const float* W_hn = (const float*)d_in[10]; const float* b_hn = (const float*)d_in[11];
    const float* W_fc = (const float*)d_in[12]; const float* b_fc = (const float*)d_in[13];
    float* out = (float*)d_out;

    char* ws = (char*)d_ws;
    size_t off = 0;
    auto alloc = [&](size_t bytes) -> char* {
        char* p = ws + off;
        off += (bytes + 255) & ~(size_t)255;
        return p;
    };
    const size_t NB  = (size_t)N_NODES * DDIM * 4;    // 20.5 MB fp32
    const size_t NBH = (size_t)N_NODES * DDIM * 2;    // 10.2 MB bf16
    // total ~293 MB (ws >= 640 MB per round-4 fill profile)
    u16*   xall    = (u16*)alloc((size_t)N_NODES * XSTR * 2);   // 81.9 MB
    u16*   xaall   = (u16*)alloc((size_t)N_NODES * XSTR * 2);   // 81.9 MB
    float* G       = (float*)alloc((size_t)N_NODES * G4 * 4);   // 81.9 MB
    float* h       = (float*)alloc(NB);
    u16*   hbf     = (u16*)alloc(NBH);
    u16*   ha      = (u16*)alloc(NBH);
    u16*   BTA     = (u16*)alloc((size_t)G4 * DDIM * 2);
    u16*   BTB     = (u16*)alloc((size_t)G4 * DDIM * 2);
    float* bias4   = (float*)alloc(G4 * 4);
    int*   cnt     = (int*)alloc(N_NODES * 4);
    int*   cursor  = (int*)alloc(N_NODES * 4);
    int*   rowptr  = (int*)alloc((N_NODES + 1) * 4);
    int*   csr_src = (int*)alloc(NE * 4);
    float* csr_nrm = (float*)alloc(NE * 4);
    float* dis     = (float*)alloc(N_NODES * 4);
    float* snorm   = (float*)alloc(N_NODES * 4);

    hipMemsetAsync(cnt, 0, N_NODES * 4, stream);
    hipMemsetAsync(cursor, 0, N_NODES * 4, stream);
    hipMemsetAsync(h, 0, NB, stream);
    hipMemsetAsync(hbf, 0, NBH, stream);

    const int TB = 256;
    // CSR build + norms
    k_count<<<(NE + TB - 1) / TB, TB, 0, stream>>>(dst, cnt);
    k_degnorm<<<(N_NODES + TB - 1) / TB, TB, 0, stream>>>(cnt, dis, snorm);
    k_scan<<<1, 256, 0, stream>>>(cnt, rowptr);
    k_fill<<<(NE + TB - 1) / TB, TB, 0, stream>>>(src, dst, rowptr, cursor, dis,
                                                  csr_src, csr_nrm);
    // packed transposed bf16 weights + fused biases
    k_pack4T<<<(G4 * DDIM + TB - 1) / TB, TB, 0, stream>>>(W_xr, W_xz, W_hn, W_hn, BTA);
    k_pack4T<<<(G4 * DDIM + TB - 1) / TB, TB, 0, stream>>>(W_hr, W_hz, W_hn, W_hn, BTB);
    k_packb4<<<(G4 + TB - 1) / TB, TB, 0, stream>>>(b_xr, b_hr, b_xz, b_hz, b_hn, bias4);

    // batched x-side prep (out of the recurrence)
    k_x2bf_all<<<(N_NODES * 512 + TB - 1) / TB, TB, 0, stream>>>(x, xall);
    int aggGrid = (N_NODES + 3) / 4;
    k_agg_x<<<aggGrid, TB, 0, stream>>>(xall, rowptr, csr_src, csr_nrm, snorm, xaall);

    dim3 gGate((N_NODES + 127) / 128, 8);   // 157 x 8 col-tiles of G[.][1024]
    dim3 gfc((N_NODES + 127) / 128, 1);
    int gruGrid = (N_NODES * DDIM / 4 + TB - 1) / TB;

    for (int t = 0; t < T_STEPS; t++) {
        k_agg_bf<<<aggGrid, TB, 0, stream>>>(hbf, rowptr, csr_src, csr_nrm, snorm, ha);
        k_gemm_gate<<<gGate, TB, 0, stream>>>(xaall + t * DDIM, XSTR, ha, BTA, BTB,
                                              bias4, G, N_NODES);
        k_gru<<<gruGrid, TB, 0, stream>>>(G, h, hbf);
    }
    // final FC in fp32: out = h @ W_fc + b_fc
    k_gemm<<<gfc, TB, 0, stream>>>(h, W_fc, b_fc, out, N_NODES, DOUT, DDIM);
}

// Round 6
// 1215.576 us; speedup vs baseline: 2.6577x; 1.1824x over previous
//
#include <hip/hip_runtime.h>
#include <hip/hip_bf16.h>
#include <math.h>

// Problem constants (fixed by the reference)
#define N_NODES 20000
#define T_STEPS 8
#define DDIM    256      // D_IN == D_HID == K
#define DOUT    64
#define NE      320000
#define XSTR    2048     // T_STEPS * DDIM

typedef unsigned short u16;
typedef __attribute__((ext_vector_type(8))) short  short8;   // 8 bf16 = 4 VGPR
typedef __attribute__((ext_vector_type(4))) float  f32x4;

__device__ __forceinline__ float bf2f(u16 u) {
    union { unsigned int i; float f; } v; v.i = ((unsigned int)u) << 16; return v.f;
}
__device__ __forceinline__ u16 f2bf(float f) {   // RNE
    union { float f; unsigned int i; } v; v.f = f;
    unsigned int r = v.i + 0x7fff + ((v.i >> 16) & 1);
    return (u16)(r >> 16);
}

// ---------------------------------------------------------------------------
// CSR build
// ---------------------------------------------------------------------------
__global__ void k_count(const int* __restrict__ dst, int* __restrict__ cnt) {
    int e = blockIdx.x * blockDim.x + threadIdx.x;
    if (e < NE) atomicAdd(&cnt[dst[e]], 1);
}

__global__ void k_degnorm(const int* __restrict__ cnt, float* __restrict__ dis,
                          float* __restrict__ snorm) {
    int n = blockIdx.x * blockDim.x + threadIdx.x;
    if (n < N_NODES) {
        float deg = (float)(cnt[n] + 1);   // +1 self loop
        dis[n]   = rsqrtf(deg);
        snorm[n] = 1.0f / deg;
    }
}

__global__ void k_scan(const int* __restrict__ cnt, int* __restrict__ rowptr) {
    __shared__ int sums[256];
    const int CH = (N_NODES + 255) / 256;   // 79
    int t = threadIdx.x;
    int beg = t * CH;
    int end = beg + CH; if (end > N_NODES) end = N_NODES;
    int s = 0;
    for (int i = beg; i < end; i++) s += cnt[i];
    sums[t] = s;
    __syncthreads();
    if (t == 0) {
        int run = 0;
        for (int i = 0; i < 256; i++) { int v = sums[i]; sums[i] = run; run += v; }
    }
    __syncthreads();
    if (beg < N_NODES) {
        int run = sums[t];
        for (int i = beg; i < end; i++) { rowptr[i] = run; run += cnt[i]; }
        if (end == N_NODES) rowptr[N_NODES] = run;
    }
}

__global__ void k_fill(const int* __restrict__ src, const int* __restrict__ dst,
                       const int* __restrict__ rowptr, int* __restrict__ cursor,
                       const float* __restrict__ dis, int* __restrict__ csr_src,
                       float* __restrict__ csr_norm) {
    int e = blockIdx.x * blockDim.x + threadIdx.x;
    if (e < NE) {
        int d = dst[e], s = src[e];
        int pos = atomicAdd(&cursor[d], 1);
        int i = rowptr[d] + pos;
        if (i < NE) {
            csr_src[i]  = s;
            csr_norm[i] = dis[s] * dis[d];
        }
    }
}

// ---------------------------------------------------------------------------
// Weight pack: BTpack[by][tile][c][k], by=0..3 (64-col groups), tile=0..5:
// {0:W_xr, 1:W_xz, 2:W_hn, 3:W_hr, 4:W_hz, 5:W_hn}, value = W[k][by*64+c] bf16
// ---------------------------------------------------------------------------
__global__ void k_pack6(const float* __restrict__ Wxr, const float* __restrict__ Wxz,
                        const float* __restrict__ Whn, const float* __restrict__ Whr,
                        const float* __restrict__ Whz, u16* __restrict__ out) {
    int i = blockIdx.x * blockDim.x + threadIdx.x;   // over 4*6*64*256
    if (i >= 4 * 6 * 64 * 256) return;
    int k    = i & 255;
    int c    = (i >> 8) & 63;
    int tile = (i >> 14) % 6;
    int by   = i / (6 * 64 * 256);
    const float* W;
    switch (tile) {
        case 0: W = Wxr; break; case 1: W = Wxz; break; case 2: W = Whn; break;
        case 3: W = Whr; break; case 4: W = Whz; break; default: W = Whn; break;
    }
    out[i] = f2bf(W[k * DDIM + by * 64 + c]);
}
// bias3 = [b_xr+b_hr | b_xz+b_hz | b_hn]
__global__ void k_packb3(const float* __restrict__ bxr, const float* __restrict__ bhr,
                         const float* __restrict__ bxz, const float* __restrict__ bhz,
                         const float* __restrict__ bhn, float* __restrict__ bout) {
    int c = blockIdx.x * blockDim.x + threadIdx.x;
    if (c < 3 * DDIM) {
        float v;
        if (c < 256)      v = bxr[c] + bhr[c];
        else if (c < 512) v = bxz[c - 256] + bhz[c - 256];
        else              v = bhn[c - 512];
        bout[c] = v;
    }
}

// ---------------------------------------------------------------------------
// all-timestep x -> bf16 [N][2048]
// ---------------------------------------------------------------------------
__global__ __launch_bounds__(256) void k_x2bf_all(const float* __restrict__ x,
                                                  u16* __restrict__ out) {
    int i = blockIdx.x * blockDim.x + threadIdx.x;   // over N*512 ushort4 chunks
    if (i >= N_NODES * 512) return;
    size_t o = (size_t)i << 2;
    float4 v = *(const float4*)(x + o);
    ushort4 u; u.x = f2bf(v.x); u.y = f2bf(v.y); u.z = f2bf(v.z); u.w = f2bf(v.w);
    *(ushort4*)(out + o) = u;
}

// ---------------------------------------------------------------------------
// Batched x aggregation over all 8 timesteps (edge-unrolled x2 for MLP)
// ---------------------------------------------------------------------------
__global__ __launch_bounds__(256) void k_agg_x(const u16* __restrict__ xall,
                      const int* __restrict__ rowptr, const int* __restrict__ csr_src,
                      const float* __restrict__ csr_norm, const float* __restrict__ snorm,
                      u16* __restrict__ xaall) {
    int n = blockIdx.x * 4 + (threadIdx.x >> 6);
    if (n >= N_NODES) return;
    int lane = threadIdx.x & 63;
    int c4 = lane << 2;
    float sn = snorm[n];
    float acc[8][4];
    const u16* selfp = xall + (size_t)n * XSTR + c4;
#pragma unroll
    for (int t = 0; t < 8; t++) {
        ushort4 v = *(const ushort4*)(selfp + t * DDIM);
        acc[t][0] = bf2f(v.x) * sn; acc[t][1] = bf2f(v.y) * sn;
        acc[t][2] = bf2f(v.z) * sn; acc[t][3] = bf2f(v.w) * sn;
    }
    int beg = rowptr[n], end = rowptr[n + 1];
    int i = beg;
    for (; i + 1 < end; i += 2) {
        const u16* sp0 = xall + (size_t)csr_src[i] * XSTR + c4;
        const u16* sp1 = xall + (size_t)csr_src[i + 1] * XSTR + c4;
        float w0 = csr_norm[i], w1 = csr_norm[i + 1];
        ushort4 g0[8], g1[8];
#pragma unroll
        for (int t = 0; t < 8; t++) g0[t] = *(const ushort4*)(sp0 + t * DDIM);
#pragma unroll
        for (int t = 0; t < 8; t++) g1[t] = *(const ushort4*)(sp1 + t * DDIM);
#pragma unroll
        for (int t = 0; t < 8; t++) {
            acc[t][0] = fmaf(bf2f(g0[t].x), w0, fmaf(bf2f(g1[t].x), w1, acc[t][0]));
            acc[t][1] = fmaf(bf2f(g0[t].y), w0, fmaf(bf2f(g1[t].y), w1, acc[t][1]));
            acc[t][2] = fmaf(bf2f(g0[t].z), w0, fmaf(bf2f(g1[t].z), w1, acc[t][2]));
            acc[t][3] = fmaf(bf2f(g0[t].w), w0, fmaf(bf2f(g1[t].w), w1, acc[t][3]));
        }
    }
    if (i < end) {
        const u16* sp = xall + (size_t)csr_src[i] * XSTR + c4;
        float w = csr_norm[i];
#pragma unroll
        for (int t = 0; t < 8; t++) {
            ushort4 g = *(const ushort4*)(sp + t * DDIM);
            acc[t][0] = fmaf(bf2f(g.x), w, acc[t][0]);
            acc[t][1] = fmaf(bf2f(g.y), w, acc[t][1]);
            acc[t][2] = fmaf(bf2f(g.z), w, acc[t][2]);
            acc[t][3] = fmaf(bf2f(g.w), w, acc[t][3]);
        }
    }
    u16* op = xaall + (size_t)n * XSTR + c4;
#pragma unroll
    for (int t = 0; t < 8; t++) {
        ushort4 o;
        o.x = f2bf(acc[t][0]); o.y = f2bf(acc[t][1]);
        o.z = f2bf(acc[t][2]); o.w = f2bf(acc[t][3]);
        *(ushort4*)(op + t * DDIM) = o;
    }
}

// ---------------------------------------------------------------------------
// Per-step h aggregation (bf16 in/out), edge-unrolled x2
// ---------------------------------------------------------------------------
__global__ __launch_bounds__(256) void k_agg_bf(const u16* __restrict__ in,
                      const int* __restrict__ rowptr, const int* __restrict__ csr_src,
                      const float* __restrict__ csr_norm, const float* __restrict__ snorm,
                      u16* __restrict__ out) {
    int n = blockIdx.x * 4 + (threadIdx.x >> 6);
    if (n >= N_NODES) return;
    int lane = threadIdx.x & 63;
    int c4 = lane << 2;
    float sn = snorm[n];
    ushort4 v = *(const ushort4*)(in + (size_t)n * DDIM + c4);
    float a0 = bf2f(v.x) * sn, a1 = bf2f(v.y) * sn, a2 = bf2f(v.z) * sn, a3 = bf2f(v.w) * sn;
    int beg = rowptr[n], end = rowptr[n + 1];
    int i = beg;
    for (; i + 1 < end; i += 2) {
        ushort4 g0 = *(const ushort4*)(in + (size_t)csr_src[i] * DDIM + c4);
        ushort4 g1 = *(const ushort4*)(in + (size_t)csr_src[i + 1] * DDIM + c4);
        float w0 = csr_norm[i], w1 = csr_norm[i + 1];
        a0 = fmaf(bf2f(g0.x), w0, fmaf(bf2f(g1.x), w1, a0));
        a1 = fmaf(bf2f(g0.y), w0, fmaf(bf2f(g1.y), w1, a1));
        a2 = fmaf(bf2f(g0.z), w0, fmaf(bf2f(g1.z), w1, a2));
        a3 = fmaf(bf2f(g0.w), w0, fmaf(bf2f(g1.w), w1, a3));
    }
    if (i < end) {
        ushort4 g = *(const ushort4*)(in + (size_t)csr_src[i] * DDIM + c4);
        float w = csr_norm[i];
        a0 = fmaf(bf2f(g.x), w, a0); a1 = fmaf(bf2f(g.y), w, a1);
        a2 = fmaf(bf2f(g.z), w, a2); a3 = fmaf(bf2f(g.w), w, a3);
    }
    ushort4 o; o.x = f2bf(a0); o.y = f2bf(a1); o.z = f2bf(a2); o.w = f2bf(a3);
    *(ushort4*)(out + (size_t)n * DDIM + c4) = o;
}

// ---------------------------------------------------------------------------
// Fused gate GEMM + GRU update.
// Block: 64 rows x 64 h-cols (blockIdx.y = by in 0..3). 4 waves (2 row x 2 col).
// Per wave: 32 rows x 32 cols, 4 gate accums [2][2] f32x4 each.
//   r  = xa@W_xr + ha@W_hr    z = xa@W_xz + ha@W_hz
//   nx = xa@W_hn              nh = ha@W_hn
// h_new = (1-sig(z+bz))*h + sig(z+bz)*tanh(nx+bn + sig(r+br)*(nh+bn))
// LDS chunk-XOR swizzle on A and B tiles (involution on stage + read).
// ---------------------------------------------------------------------------
__device__ __forceinline__ float sigm(float x) { return 1.0f / (1.0f + expf(-x)); }

__global__ __launch_bounds__(256) void k_gate_gru(const u16* __restrict__ xa, int ldax,
        const u16* __restrict__ ha, const u16* __restrict__ BTpack,
        const float* __restrict__ bias3, float* __restrict__ h, u16* __restrict__ hbf,
        int M) {
    __shared__ u16 Axs[64 * 32];     // 4KB
    __shared__ u16 Ahs[64 * 32];     // 4KB
    __shared__ u16 Bs[6 * 64 * 32];  // 24KB
    int tid = threadIdx.x;
    int w = tid >> 6, lane = tid & 63;
    int rowBase = blockIdx.x * 64;
    int by = blockIdx.y;             // 0..3

    // staging: lane covers row srow, pre-swizzled chunk of the 32k row
    int srow  = lane >> 2;                       // 0..15
    int chunk = (lane & 3) ^ ((lane >> 3) & 3);  // involution partner
    int sege  = chunk * 8;                       // elements
    int arow = rowBase + w * 16 + srow;
    if (arow > M - 1) arow = M - 1;
    size_t xoff = (size_t)arow * ldax + sege;
    size_t hoff = (size_t)arow * DDIM + sege;
    u16* ldsAx = &Axs[w * 16 * 32];
    u16* ldsAh = &Ahs[w * 16 * 32];
    const u16* Bbase = BTpack + (size_t)by * (6 * 64 * 256);

    f32x4 ar[2][2], az[2][2], anx[2][2], anh[2][2];
#pragma unroll
    for (int m = 0; m < 2; m++)
#pragma unroll
        for (int n = 0; n < 2; n++) {
            ar[m][n] = (f32x4){0.f,0.f,0.f,0.f}; az[m][n] = (f32x4){0.f,0.f,0.f,0.f};
            anx[m][n] = (f32x4){0.f,0.f,0.f,0.f}; anh[m][n] = (f32x4){0.f,0.f,0.f,0.f};
        }

    int kq = lane >> 4, lr = lane & 15;
    int kqs = (kq ^ ((lr >> 1) & 3)) << 3;       // swizzled read chunk (elems)

    for (int k0 = 0; k0 < DDIM; k0 += 32) {
        __builtin_amdgcn_global_load_lds(
            (const __attribute__((address_space(1))) void*)(xa + xoff + k0),
            (__attribute__((address_space(3))) void*)ldsAx, 16, 0, 0);
        __builtin_amdgcn_global_load_lds(
            (const __attribute__((address_space(1))) void*)(ha + hoff + k0),
            (__attribute__((address_space(3))) void*)ldsAh, 16, 0, 0);
#pragma unroll
        for (int j6 = 0; j6 < 6; j6++) {
            int j = w * 6 + j6;
            int tile = j >> 2, q = j & 3;
            const u16* src = Bbase + ((size_t)tile * 64 + q * 16 + srow) * 256 + k0 + sege;
            u16* dst = &Bs[tile * 2048 + q * 512];
            __builtin_amdgcn_global_load_lds(
                (const __attribute__((address_space(1))) void*)src,
                (__attribute__((address_space(3))) void*)dst, 16, 0, 0);
        }
        __syncthreads();

        short8 ax[2], ah[2], bf[6][2];
#pragma unroll
        for (int m = 0; m < 2; m++) {
            int r = (w >> 1) * 32 + m * 16 + lr;
            ax[m] = *(const short8*)&Axs[r * 32 + kqs];
            ah[m] = *(const short8*)&Ahs[r * 32 + kqs];
        }
#pragma unroll
        for (int t = 0; t < 6; t++)
#pragma unroll
            for (int n = 0; n < 2; n++) {
                int c = (w & 1) * 32 + n * 16 + lr;
                bf[t][n] = *(const short8*)&Bs[t * 2048 + c * 32 + kqs];
            }
#pragma unroll
        for (int m = 0; m < 2; m++)
#pragma unroll
            for (int n = 0; n < 2; n++) {
                ar[m][n]  = __builtin_amdgcn_mfma_f32_16x16x32_bf16(ax[m], bf[0][n], ar[m][n], 0, 0, 0);
                ar[m][n]  = __builtin_amdgcn_mfma_f32_16x16x32_bf16(ah[m], bf[3][n], ar[m][n], 0, 0, 0);
                az[m][n]  = __builtin_amdgcn_mfma_f32_16x16x32_bf16(ax[m], bf[1][n], az[m][n], 0, 0, 0);
                az[m][n]  = __builtin_amdgcn_mfma_f32_16x16x32_bf16(ah[m], bf[4][n], az[m][n], 0, 0, 0);
                anx[m][n] = __builtin_amdgcn_mfma_f32_16x16x32_bf16(ax[m], bf[2][n], anx[m][n], 0, 0, 0);
                anh[m][n] = __builtin_amdgcn_mfma_f32_16x16x32_bf16(ah[m], bf[5][n], anh[m][n], 0, 0, 0);
            }
        __syncthreads();
    }

    // fused GRU epilogue
#pragma unroll
    for (int n = 0; n < 2; n++) {
        int col = by * 64 + (w & 1) * 32 + n * 16 + lr;
        float br = bias3[col], bz = bias3[256 + col], bn = bias3[512 + col];
#pragma unroll
        for (int m = 0; m < 2; m++) {
            int row0 = rowBase + (w >> 1) * 32 + m * 16 + kq * 4;
#pragma unroll
            for (int j = 0; j < 4; j++) {
                int row = row0 + j;
                if (row < M) {
                    float r = sigm(ar[m][n][j] + br);
                    float z = sigm(az[m][n][j] + bz);
                    float nn = tanhf(anx[m][n][j] + bn + r * (anh[m][n][j] + bn));
                    size_t idx = (size_t)row * DDIM + col;
                    float hv = h[idx];
                    hv = (1.0f - z) * hv + z * nn;
                    h[idx] = hv;
                    hbf[idx] = f2bf(hv);
                }
            }
        }
    }
}

// ---------------------------------------------------------------------------
// fp32 SIMT GEMM (final FC only)
// ---------------------------------------------------------------------------
__global__ __launch_bounds__(256) void k_gemm(const float* __restrict__ A,
        const float* __restrict__ B, const float* __restrict__ bias,
        float* __restrict__ C, int M, int N, int K) {
    __shared__ float Asm[16][132];
    __shared__ float Bsm[16][128];
    int tid = threadIdx.x;
    int tx = tid & 15, ty = tid >> 4;
    int rowBase = blockIdx.x * 128;
    int colBase = blockIdx.y * 128;

    float acc[8][8];
#pragma unroll
    for (int i = 0; i < 8; i++)
#pragma unroll
        for (int j = 0; j < 8; j++) acc[i][j] = 0.0f;

    int arow = tid >> 1;
    int acol = (tid & 1) * 8;
    int brow = tid >> 4;
    int bcol = (tid & 15) * 8;

    bool avalid = (rowBase + arow) < M;
    const float* Aptr = A + (size_t)(rowBase + arow) * K + acol;
    int bc = colBase + bcol;
    bool bvalid = bc < N;

    for (int k0 = 0; k0 < K; k0 += 16) {
        float4 a0 = {0,0,0,0}, a1 = {0,0,0,0};
        if (avalid) {
            a0 = *(const float4*)(Aptr + k0);
            a1 = *(const float4*)(Aptr + k0 + 4);
        }
        Asm[acol + 0][arow] = a0.x; Asm[acol + 1][arow] = a0.y;
        Asm[acol + 2][arow] = a0.z; Asm[acol + 3][arow] = a0.w;
        Asm[acol + 4][arow] = a1.x; Asm[acol + 5][arow] = a1.y;
        Asm[acol + 6][arow] = a1.z; Asm[acol + 7][arow] = a1.w;

        float4 b0 = {0,0,0,0}, b1 = {0,0,0,0};
        if (bvalid) {
            const float* Bp = B + (size_t)(k0 + brow) * N + bc;
            b0 = *(const float4*)(Bp);
            b1 = *(const float4*)(Bp + 4);
        }
        *(float4*)&Bsm[brow][bcol]     = b0;
        *(float4*)&Bsm[brow][bcol + 4] = b1;
        __syncthreads();

#pragma unroll
        for (int k = 0; k < 16; k++) {
            float a[8], b[8];
            *(float4*)&a[0] = *(const float4*)&Asm[k][ty * 8];
            *(float4*)&a[4] = *(const float4*)&Asm[k][ty * 8 + 4];
            *(float4*)&b[0] = *(const float4*)&Bsm[k][tx * 8];
            *(float4*)&b[4] = *(const float4*)&Bsm[k][tx * 8 + 4];
#pragma unroll
            for (int i = 0; i < 8; i++)
#pragma unroll
                for (int j = 0; j < 8; j++)
                    acc[i][j] = fmaf(a[i], b[j], acc[i][j]);
        }
        __syncthreads();
    }

    int c0 = colBase + tx * 8;
    if (c0 < N) {
        float4 bia0 = *(const float4*)(bias + c0);
        float4 bia1 = *(const float4*)(bias + c0 + 4);
#pragma unroll
        for (int i = 0; i < 8; i++) {
            int r = rowBase + ty * 8 + i;
            if (r < M) {
                float4 o0, o1;
                o0.x = acc[i][0] + bia0.x; o0.y = acc[i][1] + bia0.y;
                o0.z = acc[i][2] + bia0.z; o0.w = acc[i][3] + bia0.w;
                o1.x = acc[i][4] + bia1.x; o1.y = acc[i][5] + bia1.y;
                o1.z = acc[i][6] + bia1.z; o1.w = acc[i][7] + bia1.w;
                *(float4*)(C + (size_t)r * N + c0)     = o0;
                *(float4*)(C + (size_t)r * N + c0 + 4) = o1;
            }
        }
    }
}

// ---------------------------------------------------------------------------
extern "C" void kernel_launch(void* const* d_in, const int* in_sizes, int n_in,
                              void* d_out, int out_size, void* d_ws, size_t ws_size,
                              hipStream_t stream) {
    const float* x    = (const float*)d_in[0];
    const int*   eidx = (const int*)d_in[1];
    const int*   src  = eidx;
    const int*   dst  = eidx + NE;
    const float* W_xr = (const float*)d_in[2];  const float* b_xr = (const float*)d_in[3];
    const float* W_hr = (const float*)d_in[4];  const float* b_hr = (const float*)d_in[5];
    const float* W_xz = (const float*)d_in[6];  const float* b_xz = (const float*)d_in[7];
    const float* W_hz = (const float*)d_in[8];  const float* b_hz = (const float*)d_in[9];
    const float* W_hn = (const float*)d_in[10]; const float* b_hn = (const float*)d_in[11];
    const float* W_fc = (const float*)d_in[12]; const float* b_fc = (const float*)d_in[13];
    float* out = (float*)d_out;

    char* ws = (char*)d_ws;
    size_t off = 0;
    auto alloc = [&](size_t bytes) -> char* {
        char* p = ws + off;
        off += (bytes + 255) & ~(size_t)255;
        return p;
    };
    const size_t NB  = (size_t)N_NODES * DDIM * 4;    // 20.5 MB fp32
    const size_t NBH = (size_t)N_NODES * DDIM * 2;    // 10.2 MB bf16
    u16*   xall    = (u16*)alloc((size_t)N_NODES * XSTR * 2);   // 81.9 MB
    u16*   xaall   = (u16*)alloc((size_t)N_NODES * XSTR * 2);   // 81.9 MB
    float* h       = (float*)alloc(NB);
    u16*   hbf     = (u16*)alloc(NBH);
    u16*   ha      = (u16*)alloc(NBH);
    u16*   BTpack  = (u16*)alloc((size_t)4 * 6 * 64 * 256 * 2); // 0.79 MB
    float* bias3   = (float*)alloc(3 * DDIM * 4);
    int*   cnt     = (int*)alloc(N_NODES * 4);
    int*   cursor  = (int*)alloc(N_NODES * 4);
    int*   rowptr  = (int*)alloc((N_NODES + 1) * 4);
    int*   csr_src = (int*)alloc(NE * 4);
    float* csr_nrm = (float*)alloc(NE * 4);
    float* dis     = (float*)alloc(N_NODES * 4);
    float* snorm   = (float*)alloc(N_NODES * 4);

    hipMemsetAsync(cnt, 0, N_NODES * 4, stream);
    hipMemsetAsync(cursor, 0, N_NODES * 4, stream);
    hipMemsetAsync(h, 0, NB, stream);
    hipMemsetAsync(hbf, 0, NBH, stream);

    const int TB = 256;
    // CSR build + norms
    k_count<<<(NE + TB - 1) / TB, TB, 0, stream>>>(dst, cnt);
    k_degnorm<<<(N_NODES + TB - 1) / TB, TB, 0, stream>>>(cnt, dis, snorm);
    k_scan<<<1, 256, 0, stream>>>(cnt, rowptr);
    k_fill<<<(NE + TB - 1) / TB, TB, 0, stream>>>(src, dst, rowptr, cursor, dis,
                                                  csr_src, csr_nrm);
    // weight/bias packing
    k_pack6<<<(4 * 6 * 64 * 256 + TB - 1) / TB, TB, 0, stream>>>(W_xr, W_xz, W_hn,
                                                                 W_hr, W_hz, BTpack);
    k_packb3<<<(3 * DDIM + TB - 1) / TB, TB, 0, stream>>>(b_xr, b_hr, b_xz, b_hz,
                                                          b_hn, bias3);

    // batched x-side prep
    k_x2bf_all<<<(N_NODES * 512 + TB - 1) / TB, TB, 0, stream>>>(x, xall);
    int aggGrid = (N_NODES + 3) / 4;
    k_agg_x<<<aggGrid, TB, 0, stream>>>(xall, rowptr, csr_src, csr_nrm, snorm, xaall);

    dim3 gGate((N_NODES + 63) / 64, 4);   // 313 x 4
    dim3 gfc((N_NODES + 127) / 128, 1);

    for (int t = 0; t < T_STEPS; t++) {
        k_agg_bf<<<aggGrid, TB, 0, stream>>>(hbf, rowptr, csr_src, csr_nrm, snorm, ha);
        k_gate_gru<<<gGate, TB, 0, stream>>>(xaall + t * DDIM, XSTR, ha, BTpack,
                                             bias3, h, hbf, N_NODES);
    }
    // final FC in fp32: out = h @ W_fc + b_fc
    k_gemm<<<gfc, TB, 0, stream>>>(h, W_fc, b_fc, out, N_NODES, DOUT, DDIM);
}